// Round 7
// baseline (111.681 us; speedup 1.0000x reference)
//
#include <hip/hip_runtime.h>
#include <math.h>

#define CAMS 6
#define CCH 256
#define HH 46
#define WW 80
#define NPIX (HH * WW)
#define HEADS 8
#define PIP 4
#define PP 4
#define KK 16
#define RADIUS_F 0.12f
#define NC 384   // combined qgemm output width: 256 offsets + 128 logits

__device__ __forceinline__ unsigned short f2bf(float f) {
    unsigned int x = __float_as_uint(f);
    unsigned int r = (x + 0x7FFFu + ((x >> 16) & 1u)) >> 16;  // RNE
    return (unsigned short)r;
}
__device__ __forceinline__ float bf2f(unsigned short u) {
    return __uint_as_float(((unsigned int)u) << 16);
}

// LDS-tiled transpose+convert: in [6][256][3680] f32 -> out [6][3680][256] bf16
__global__ void __launch_bounds__(256) feat_transpose_k(const float* __restrict__ in,
                                                        unsigned short* __restrict__ out) {
    __shared__ float tile[64][65];
    int cam = blockIdx.z;
    int r0 = blockIdx.y * 64;   // channel block
    int p0 = blockIdx.x * 64;   // pixel block
    int tj = threadIdx.x & 63;
    int ti = threadIdx.x >> 6;
    const float* src = in + ((long)cam * CCH + r0) * NPIX + p0;
#pragma unroll
    for (int k = 0; k < 64; k += 4) {
        if (p0 + tj < NPIX) tile[ti + k][tj] = src[(long)(ti + k) * NPIX + tj];
    }
    __syncthreads();
    unsigned short* dst = out + ((long)cam * NPIX + p0) * CCH + r0;
#pragma unroll
    for (int k = 0; k < 64; k += 4) {
        if (p0 + ti + k < NPIX) dst[(long)(ti + k) * CCH + tj] = f2bf(tile[tj][ti + k]);
    }
}

// Fused tiled transposes:
//  - offset_w [256][256] -> WC[:, 0:256]   (stride NC)   tiles 0..15
//  - weight_w [128][256] -> WC[:, 256:384] (stride NC)   tiles 16..23
//  - out_w    [256][256] -> outT [256][256]              tiles 24..39
__global__ void __launch_bounds__(256) wtrans_k(const float* __restrict__ offw,
                                                const float* __restrict__ ww,
                                                const float* __restrict__ outw,
                                                float* __restrict__ WC,
                                                float* __restrict__ outT) {
    __shared__ float tile[64][65];
    int b = blockIdx.x;
    const float* src;
    float* dst;
    int C, tr, tc, dstride, dcol0;
    if (b < 16)      { src = offw; dst = WC;   C = 256; tr = b >> 2;        tc = b & 3;        dstride = NC;  dcol0 = 0; }
    else if (b < 24) { src = ww;   dst = WC;   C = 256; tr = (b - 16) >> 2; tc = (b - 16) & 3; dstride = NC;  dcol0 = 256; }
    else             { src = outw; dst = outT; C = 256; tr = (b - 24) >> 2; tc = (b - 24) & 3; dstride = 256; dcol0 = 0; }
    if (b >= 16 && b < 24) { tr = (b - 16) & 1; tc = (b - 16) >> 1; }  // ww is [128][256]: 2x4 tiles
    int tj = threadIdx.x & 63;
    int ti = threadIdx.x >> 6;
#pragma unroll
    for (int k = 0; k < 64; k += 4)
        tile[ti + k][tj] = src[(long)(tr * 64 + ti + k) * C + tc * 64 + tj];
    __syncthreads();
#pragma unroll
    for (int k = 0; k < 64; k += 4)
        dst[(long)(tc * 64 + ti + k) * dstride + dcol0 + tr * 64 + tj] = tile[tj][ti + k];
}

// Combined per-query GEMM: one wave per query, lane l owns cols {l+64i}.
// cols 0..255 -> offsets = tanh(.+offB)*R ; cols 256..383 -> wl = . + wB
__global__ void __launch_bounds__(256) qgemm2_k(const float* __restrict__ query,
                                                const float* __restrict__ WC,   // [256][384]
                                                const float* __restrict__ offB,
                                                const float* __restrict__ wB,
                                                float* __restrict__ offsets,    // [N][256]
                                                float* __restrict__ wl,         // [N][128]
                                                int N) {
    __shared__ float qs[4][CCH];
    int w = threadIdx.x >> 6, l = threadIdx.x & 63;
    int n = blockIdx.x * 4 + w;
    if (n >= N) return;
    const float* qr = query + (long)n * CCH;
    qs[w][l] = qr[l];
    qs[w][l + 64] = qr[l + 64];
    qs[w][l + 128] = qr[l + 128];
    qs[w][l + 192] = qr[l + 192];
    // wave-local LDS: no cross-wave sharing -> no barrier needed

    float acc[6] = {0.f, 0.f, 0.f, 0.f, 0.f, 0.f};
    const float* wp = WC + l;
#pragma unroll 4
    for (int j = 0; j < CCH; j++) {
        float qj = qs[w][j];
        const float* row = wp + (long)j * NC;
#pragma unroll
        for (int i = 0; i < 6; i++) acc[i] = fmaf(qj, row[i * 64], acc[i]);
    }
#pragma unroll
    for (int i = 0; i < 4; i++) {
        int col = l + 64 * i;
        offsets[(long)n * CCH + col] = tanhf(acc[i] + offB[col]) * RADIUS_F;
    }
#pragma unroll
    for (int i = 4; i < 6; i++) {
        int col = l + 64 * (i - 4);
        wl[(long)n * 128 + col] = acc[i] + wB[col];
    }
}

// Per-(cam,query) sampling. One wave per task; tasks cam-major, partitioned
// into 8 contiguous ranges pinned to XCDs via blockIdx%8 (round-robin
// dispatch). Each XCD touches <=2 cams (<=3.7 MB bf16) -> L2-resident.
__global__ void __launch_bounds__(256, 4) sample_cam_k(
        const unsigned short* __restrict__ feat_t,  // [CAMS][NPIX][CCH] bf16
        const float* __restrict__ refp,             // [CAMS][N][PIP][2]
        const int* __restrict__ bev,                // [CAMS][N][PIP]
        const float* __restrict__ offsets,          // [N][256]
        const float* __restrict__ wl,               // [N][128]
        float* __restrict__ cam_out,                // [CAMS][N][256]
        int N, int per_xcd) {
    int xcd = blockIdx.x & 7;
    int local = (blockIdx.x >> 3) * 4 + (threadIdx.x >> 6);
    if (local >= per_xcd) return;
    long task = (long)xcd * per_xcd + local;
    if (task >= (long)CAMS * N) return;
    int cam = (int)(task / N);
    int n = (int)(task - (long)cam * N);

    int l = threadIdx.x & 63;
    int h = l >> 3;

    const int* bv = bev + ((long)cam * N + n) * 4;
    int m0 = bv[0], m1 = bv[1], m2 = bv[2], m3 = bv[3];
    float* outp = cam_out + ((long)cam * N + n) * CCH + (l << 2);
    if (!(m0 | m1 | m2 | m3)) {
        *(float4*)outp = make_float4(0.f, 0.f, 0.f, 0.f);
        return;
    }

    const float* rp = refp + ((long)cam * N + n) * 8;
    const float4* offn = (const float4*)(offsets + (long)n * CCH + (h << 5));
    const float4* wln = (const float4*)(wl + (long)n * 128 + (h << 4));

    float4 wl0, wl1, wl2, wl3;
    float mmax = -1e30f;
    if (m0) { wl0 = wln[0]; mmax = fmaxf(mmax, fmaxf(fmaxf(wl0.x, wl0.y), fmaxf(wl0.z, wl0.w))); }
    if (m1) { wl1 = wln[1]; mmax = fmaxf(mmax, fmaxf(fmaxf(wl1.x, wl1.y), fmaxf(wl1.z, wl1.w))); }
    if (m2) { wl2 = wln[2]; mmax = fmaxf(mmax, fmaxf(fmaxf(wl2.x, wl2.y), fmaxf(wl2.z, wl2.w))); }
    if (m3) { wl3 = wln[3]; mmax = fmaxf(mmax, fmaxf(fmaxf(wl3.x, wl3.y), fmaxf(wl3.z, wl3.w))); }

    float w_[KK];
#pragma unroll
    for (int k = 0; k < KK; k++) w_[k] = 0.f;
    float ssum = 0.f;
    if (m0) {
        w_[0] = __expf(wl0.x - mmax); w_[1] = __expf(wl0.y - mmax);
        w_[2] = __expf(wl0.z - mmax); w_[3] = __expf(wl0.w - mmax);
        ssum += w_[0] + w_[1] + w_[2] + w_[3];
    }
    if (m1) {
        w_[4] = __expf(wl1.x - mmax); w_[5] = __expf(wl1.y - mmax);
        w_[6] = __expf(wl1.z - mmax); w_[7] = __expf(wl1.w - mmax);
        ssum += w_[4] + w_[5] + w_[6] + w_[7];
    }
    if (m2) {
        w_[8] = __expf(wl2.x - mmax); w_[9] = __expf(wl2.y - mmax);
        w_[10] = __expf(wl2.z - mmax); w_[11] = __expf(wl2.w - mmax);
        ssum += w_[8] + w_[9] + w_[10] + w_[11];
    }
    if (m3) {
        w_[12] = __expf(wl3.x - mmax); w_[13] = __expf(wl3.y - mmax);
        w_[14] = __expf(wl3.z - mmax); w_[15] = __expf(wl3.w - mmax);
        ssum += w_[12] + w_[13] + w_[14] + w_[15];
    }
    float inv = 1.f / ssum;

    const ushort4* fcam = (const ushort4*)(feat_t + (long)cam * NPIX * CCH) + l;
    float ax = 0.f, ay = 0.f, az = 0.f, aw = 0.f;

#pragma unroll
    for (int pip = 0; pip < PIP; pip++) {
        int vis = (pip == 0) ? m0 : (pip == 1) ? m1 : (pip == 2) ? m2 : m3;
        if (!vis) continue;
        float rx = rp[pip * 2 + 0];
        float ry = rp[pip * 2 + 1];
        float4 oa = offn[pip * 2];
        float4 ob = offn[pip * 2 + 1];
        float px[PP] = {oa.x, oa.z, ob.x, ob.z};
        float py[PP] = {oa.y, oa.w, ob.y, ob.w};
#pragma unroll
        for (int p = 0; p < PP; p++) {
            float wgt = w_[pip * PP + p];
            float x = fmaf(rx + px[p], (float)WW, -0.5f);
            float y = fmaf(ry + py[p], (float)HH, -0.5f);
            float x0f = floorf(x), y0f = floorf(y);
            float fx = x - x0f, fy = y - y0f;
            int ix = (int)x0f, iy = (int)y0f;
            int ix0 = min(max(ix, 0), WW - 1);
            int ix1 = min(max(ix + 1, 0), WW - 1);
            int iy0 = min(max(iy, 0), HH - 1);
            int iy1 = min(max(iy + 1, 0), HH - 1);
            float wx0 = (1.f - fx) * (((ix >= 0) & (ix < WW)) ? 1.f : 0.f);
            float wx1 = fx * (((ix + 1 >= 0) & (ix + 1 < WW)) ? 1.f : 0.f);
            float wy0 = (1.f - fy) * (((iy >= 0) & (iy < HH)) ? 1.f : 0.f);
            float wy1 = fy * (((iy + 1 >= 0) & (iy + 1 < HH)) ? 1.f : 0.f);
            const ushort4 u00 = fcam[(iy0 * WW + ix0) * (CCH / 4)];
            const ushort4 u01 = fcam[(iy0 * WW + ix1) * (CCH / 4)];
            const ushort4 u10 = fcam[(iy1 * WW + ix0) * (CCH / 4)];
            const ushort4 u11 = fcam[(iy1 * WW + ix1) * (CCH / 4)];
            float a00 = wgt * wy0 * wx0;
            float a01 = wgt * wy0 * wx1;
            float a10 = wgt * wy1 * wx0;
            float a11 = wgt * wy1 * wx1;
            ax = fmaf(a00, bf2f(u00.x), ax); ay = fmaf(a00, bf2f(u00.y), ay);
            az = fmaf(a00, bf2f(u00.z), az); aw = fmaf(a00, bf2f(u00.w), aw);
            ax = fmaf(a01, bf2f(u01.x), ax); ay = fmaf(a01, bf2f(u01.y), ay);
            az = fmaf(a01, bf2f(u01.z), az); aw = fmaf(a01, bf2f(u01.w), aw);
            ax = fmaf(a10, bf2f(u10.x), ax); ay = fmaf(a10, bf2f(u10.y), ay);
            az = fmaf(a10, bf2f(u10.z), az); aw = fmaf(a10, bf2f(u10.w), aw);
            ax = fmaf(a11, bf2f(u11.x), ax); ay = fmaf(a11, bf2f(u11.y), ay);
            az = fmaf(a11, bf2f(u11.z), az); aw = fmaf(a11, bf2f(u11.w), aw);
        }
    }
    *(float4*)outp = make_float4(ax * inv, ay * inv, az * inv, aw * inv);
}

// out[n] = ((sum_cam cam_out[cam][n]) / count[n]) @ out_w^T + out_b
// One wave per query; lane l owns cols {l+64i}.
__global__ void __launch_bounds__(256) outproj2_k(const float* __restrict__ cam_out,
                                                  const int* __restrict__ bev,
                                                  const float* __restrict__ outT,  // [256][256]
                                                  const float* __restrict__ outB,
                                                  float* __restrict__ out, int N) {
    __shared__ float fs[4][CCH];
    int w = threadIdx.x >> 6, l = threadIdx.x & 63;
    int n = blockIdx.x * 4 + w;
    if (n >= N) return;

#pragma unroll
    for (int i = 0; i < 4; i++) {
        int ch = l + 64 * i;
        float sum = 0.f;
#pragma unroll
        for (int cam = 0; cam < CAMS; cam++)
            sum += cam_out[((long)cam * N + n) * CCH + ch];
        fs[w][ch] = sum;
    }
    int cnt = 0;
#pragma unroll
    for (int cam = 0; cam < CAMS; cam++) {
        const int* bv = bev + ((long)cam * N + n) * 4;   // wave-uniform -> broadcast
        cnt += (bv[0] | bv[1] | bv[2] | bv[3]) ? 1 : 0;
    }
    float inv = 1.f / (float)max(cnt, 1);
    // wave-local LDS -> no barrier

    float acc[4] = {0.f, 0.f, 0.f, 0.f};
    const float* wp = outT + l;
#pragma unroll 4
    for (int j = 0; j < CCH; j++) {
        float fj = fs[w][j];
        const float* row = wp + (long)j * CCH;
#pragma unroll
        for (int i = 0; i < 4; i++) acc[i] = fmaf(fj, row[i * 64], acc[i]);
    }
#pragma unroll
    for (int i = 0; i < 4; i++) {
        int col = l + 64 * i;
        out[(long)n * CCH + col] = fmaf(acc[i], inv, outB[col]);
    }
}

extern "C" void kernel_launch(void* const* d_in, const int* in_sizes, int n_in,
                              void* d_out, int out_size, void* d_ws, size_t ws_size,
                              hipStream_t stream) {
    const float* query    = (const float*)d_in[0];
    const float* imfeat   = (const float*)d_in[1];
    const float* refp     = (const float*)d_in[2];
    const int*   bev      = (const int*)d_in[3];
    const float* offset_w = (const float*)d_in[4];
    const float* offset_b = (const float*)d_in[5];
    const float* weight_w = (const float*)d_in[6];
    const float* weight_b = (const float*)d_in[7];
    const float* out_w    = (const float*)d_in[8];
    const float* out_b    = (const float*)d_in[9];
    float* out = (float*)d_out;

    int N = in_sizes[0] / CCH;  // 2500

    float* ws = (float*)d_ws;
    unsigned short* feat_t = (unsigned short*)ws;              // 6*3680*256 bf16
    float* WC     = ws + (size_t)CAMS * NPIX * CCH / 2;        // 256*384
    float* outT   = WC + (size_t)CCH * NC;                     // 256*256
    float* offs   = outT + (size_t)CCH * CCH;                  // N*256
    float* wl     = offs + (size_t)N * CCH;                    // N*128
    float* camob  = wl + (size_t)N * 128;                      // CAMS*N*256

    feat_transpose_k<<<dim3((NPIX + 63) / 64, CCH / 64, CAMS), 256, 0, stream>>>(imfeat, feat_t);
    wtrans_k<<<40, 256, 0, stream>>>(offset_w, weight_w, out_w, WC, outT);

    qgemm2_k<<<(N + 3) / 4, 256, 0, stream>>>(query, WC, offset_b, weight_b, offs, wl, N);

    int T = CAMS * N;
    int per_xcd = (T + 7) / 8;
    int blocks = 8 * ((per_xcd + 3) / 4);
    sample_cam_k<<<blocks, 256, 0, stream>>>(feat_t, refp, bev, offs, wl, camob,
                                             N, per_xcd);

    outproj2_k<<<(N + 3) / 4, 256, 0, stream>>>(camob, bev, outT, out_b, out, N);
}

// Round 8
// 97.136 us; speedup vs baseline: 1.1497x; 1.1497x over previous
//
#include <hip/hip_runtime.h>
#include <math.h>

#define CAMS 6
#define CCH 256
#define HH 46
#define WW 80
#define NPIX (HH * WW)
#define HEADS 8
#define PIP 4
#define PP 4
#define KK 16
#define RADIUS_F 0.12f
#define NC 384   // combined qgemm output width: 256 offsets + 128 logits

__device__ __forceinline__ unsigned short f2bf(float f) {
    unsigned int x = __float_as_uint(f);
    unsigned int r = (x + 0x7FFFu + ((x >> 16) & 1u)) >> 16;  // RNE
    return (unsigned short)r;
}
__device__ __forceinline__ float bf2f(unsigned short u) {
    return __uint_as_float(((unsigned int)u) << 16);
}

// LDS-tiled transpose+convert: in [6][256][3680] f32 -> out [6][3680][256] bf16
__global__ void __launch_bounds__(256) feat_transpose_k(const float* __restrict__ in,
                                                        unsigned short* __restrict__ out) {
    __shared__ float tile[64][65];
    int cam = blockIdx.z;
    int r0 = blockIdx.y * 64;   // channel block
    int p0 = blockIdx.x * 64;   // pixel block
    int tj = threadIdx.x & 63;
    int ti = threadIdx.x >> 6;
    const float* src = in + ((long)cam * CCH + r0) * NPIX + p0;
#pragma unroll
    for (int k = 0; k < 64; k += 4) {
        if (p0 + tj < NPIX) tile[ti + k][tj] = src[(long)(ti + k) * NPIX + tj];
    }
    __syncthreads();
    unsigned short* dst = out + ((long)cam * NPIX + p0) * CCH + r0;
#pragma unroll
    for (int k = 0; k < 64; k += 4) {
        if (p0 + ti + k < NPIX) dst[(long)(ti + k) * CCH + tj] = f2bf(tile[tj][ti + k]);
    }
}

// Fused tiled transposes:
//  - offset_w [256][256] -> WC[:, 0:256]   (stride NC)   tiles 0..15
//  - weight_w [128][256] -> WC[:, 256:384] (stride NC)   tiles 16..23
//  - out_w    [256][256] -> outT [256][256]              tiles 24..39
__global__ void __launch_bounds__(256) wtrans_k(const float* __restrict__ offw,
                                                const float* __restrict__ ww,
                                                const float* __restrict__ outw,
                                                float* __restrict__ WC,
                                                float* __restrict__ outT) {
    __shared__ float tile[64][65];
    int b = blockIdx.x;
    const float* src;
    float* dst;
    int C, tr, tc, dstride, dcol0;
    if (b < 16)      { src = offw; dst = WC;   C = 256; tr = b >> 2;        tc = b & 3;        dstride = NC;  dcol0 = 0; }
    else if (b < 24) { src = ww;   dst = WC;   C = 256; tr = (b - 16) >> 2; tc = (b - 16) & 3; dstride = NC;  dcol0 = 256; }
    else             { src = outw; dst = outT; C = 256; tr = (b - 24) >> 2; tc = (b - 24) & 3; dstride = 256; dcol0 = 0; }
    if (b >= 16 && b < 24) { tr = (b - 16) & 1; tc = (b - 16) >> 1; }  // ww is [128][256]: 2x4 tiles
    int tj = threadIdx.x & 63;
    int ti = threadIdx.x >> 6;
#pragma unroll
    for (int k = 0; k < 64; k += 4)
        tile[ti + k][tj] = src[(long)(tr * 64 + ti + k) * C + tc * 64 + tj];
    __syncthreads();
#pragma unroll
    for (int k = 0; k < 64; k += 4)
        dst[(long)(tc * 64 + ti + k) * dstride + dcol0 + tr * 64 + tj] = tile[tj][ti + k];
}

// Register-blocked f32 GEMM for the query projections.
// Block: 256 thr = 4 waves; covers 32 queries x 64 cols. Wave w owns queries
// [8w,8w+8), lane l owns col cg*64+l -> acc[8]. Weight load amortized 8x.
// q staged in LDS [jg][m][4] with XOR-swizzled m (write ~4-way conflict on 8
// instrs; GEMM reads are uniform-address broadcasts, conflict-free).
__global__ void __launch_bounds__(256) qgemm3_k(const float* __restrict__ query,
                                                const float* __restrict__ WC,   // [256][384]
                                                const float* __restrict__ offB,
                                                const float* __restrict__ wB,
                                                float* __restrict__ offsets,    // [N][256]
                                                float* __restrict__ wl,         // [N][128]
                                                int N) {
    __shared__ float qt[64][32][4];   // [jg][m^][jj]; q[4jg+jj][m] at [jg][m^(jg&31)][jj]
    int t = threadIdx.x;
    int w = t >> 6, l = t & 63;
    int m0 = blockIdx.x * 32;
    int col = blockIdx.y * 64 + l;    // 0..383

#pragma unroll
    for (int i = 0; i < 8; i++) {
        int mm = i * 4 + w;           // wave-uniform
        int gm = m0 + mm;
        float4 v = make_float4(0.f, 0.f, 0.f, 0.f);
        if (gm < N) v = *(const float4*)(query + (long)gm * CCH + (l << 2));
        *(float4*)&qt[l][mm ^ (l & 31)][0] = v;
    }
    __syncthreads();

    int mb = w * 8;
    float acc[8] = {0.f, 0.f, 0.f, 0.f, 0.f, 0.f, 0.f, 0.f};
#pragma unroll 2
    for (int jg = 0; jg < 64; jg++) {
        const float* rp = WC + (long)(jg * 4) * NC + col;
        float w0 = rp[0];
        float w1 = rp[NC];
        float w2 = rp[2 * NC];
        float w3 = rp[3 * NC];
        int sw = jg & 31;
#pragma unroll
        for (int r = 0; r < 8; r++) {
            const float4 qv = *(const float4*)&qt[jg][(mb + r) ^ sw][0];
            acc[r] = fmaf(qv.w, w3, fmaf(qv.z, w2, fmaf(qv.y, w1, fmaf(qv.x, w0, acc[r]))));
        }
    }

    if (col < 256) {
        float b = offB[col];
#pragma unroll
        for (int r = 0; r < 8; r++) {
            int gm = m0 + mb + r;
            if (gm < N) offsets[(long)gm * CCH + col] = tanhf(acc[r] + b) * RADIUS_F;
        }
    } else {
        int c2 = col - 256;
        float b = wB[c2];
#pragma unroll
        for (int r = 0; r < 8; r++) {
            int gm = m0 + mb + r;
            if (gm < N) wl[(long)gm * 128 + c2] = acc[r] + b;
        }
    }
}

// Per-(cam,query) sampling. One wave per task; tasks cam-major, partitioned
// into 8 contiguous ranges pinned to XCDs via blockIdx%8 (round-robin
// dispatch). Each XCD touches <=2 cams (<=3.7 MB bf16) -> L2-resident.
__global__ void __launch_bounds__(256, 4) sample_cam_k(
        const unsigned short* __restrict__ feat_t,  // [CAMS][NPIX][CCH] bf16
        const float* __restrict__ refp,             // [CAMS][N][PIP][2]
        const int* __restrict__ bev,                // [CAMS][N][PIP]
        const float* __restrict__ offsets,          // [N][256]
        const float* __restrict__ wl,               // [N][128]
        float* __restrict__ cam_out,                // [CAMS][N][256]
        int N, int per_xcd) {
    int xcd = blockIdx.x & 7;
    int local = (blockIdx.x >> 3) * 4 + (threadIdx.x >> 6);
    if (local >= per_xcd) return;
    long task = (long)xcd * per_xcd + local;
    if (task >= (long)CAMS * N) return;
    int cam = (int)(task / N);
    int n = (int)(task - (long)cam * N);

    int l = threadIdx.x & 63;
    int h = l >> 3;

    const int* bv = bev + ((long)cam * N + n) * 4;
    int m0 = bv[0], m1 = bv[1], m2 = bv[2], m3 = bv[3];
    float* outp = cam_out + ((long)cam * N + n) * CCH + (l << 2);
    if (!(m0 | m1 | m2 | m3)) {
        *(float4*)outp = make_float4(0.f, 0.f, 0.f, 0.f);
        return;
    }

    const float* rp = refp + ((long)cam * N + n) * 8;
    const float4* offn = (const float4*)(offsets + (long)n * CCH + (h << 5));
    const float4* wln = (const float4*)(wl + (long)n * 128 + (h << 4));

    float4 wl0, wl1, wl2, wl3;
    float mmax = -1e30f;
    if (m0) { wl0 = wln[0]; mmax = fmaxf(mmax, fmaxf(fmaxf(wl0.x, wl0.y), fmaxf(wl0.z, wl0.w))); }
    if (m1) { wl1 = wln[1]; mmax = fmaxf(mmax, fmaxf(fmaxf(wl1.x, wl1.y), fmaxf(wl1.z, wl1.w))); }
    if (m2) { wl2 = wln[2]; mmax = fmaxf(mmax, fmaxf(fmaxf(wl2.x, wl2.y), fmaxf(wl2.z, wl2.w))); }
    if (m3) { wl3 = wln[3]; mmax = fmaxf(mmax, fmaxf(fmaxf(wl3.x, wl3.y), fmaxf(wl3.z, wl3.w))); }

    float w_[KK];
#pragma unroll
    for (int k = 0; k < KK; k++) w_[k] = 0.f;
    float ssum = 0.f;
    if (m0) {
        w_[0] = __expf(wl0.x - mmax); w_[1] = __expf(wl0.y - mmax);
        w_[2] = __expf(wl0.z - mmax); w_[3] = __expf(wl0.w - mmax);
        ssum += w_[0] + w_[1] + w_[2] + w_[3];
    }
    if (m1) {
        w_[4] = __expf(wl1.x - mmax); w_[5] = __expf(wl1.y - mmax);
        w_[6] = __expf(wl1.z - mmax); w_[7] = __expf(wl1.w - mmax);
        ssum += w_[4] + w_[5] + w_[6] + w_[7];
    }
    if (m2) {
        w_[8] = __expf(wl2.x - mmax); w_[9] = __expf(wl2.y - mmax);
        w_[10] = __expf(wl2.z - mmax); w_[11] = __expf(wl2.w - mmax);
        ssum += w_[8] + w_[9] + w_[10] + w_[11];
    }
    if (m3) {
        w_[12] = __expf(wl3.x - mmax); w_[13] = __expf(wl3.y - mmax);
        w_[14] = __expf(wl3.z - mmax); w_[15] = __expf(wl3.w - mmax);
        ssum += w_[12] + w_[13] + w_[14] + w_[15];
    }
    float inv = 1.f / ssum;

    const ushort4* fcam = (const ushort4*)(feat_t + (long)cam * NPIX * CCH) + l;
    float ax = 0.f, ay = 0.f, az = 0.f, aw = 0.f;

#pragma unroll
    for (int pip = 0; pip < PIP; pip++) {
        int vis = (pip == 0) ? m0 : (pip == 1) ? m1 : (pip == 2) ? m2 : m3;
        if (!vis) continue;
        float rx = rp[pip * 2 + 0];
        float ry = rp[pip * 2 + 1];
        float4 oa = offn[pip * 2];
        float4 ob = offn[pip * 2 + 1];
        float px[PP] = {oa.x, oa.z, ob.x, ob.z};
        float py[PP] = {oa.y, oa.w, ob.y, ob.w};
#pragma unroll
        for (int p = 0; p < PP; p++) {
            float wgt = w_[pip * PP + p];
            float x = fmaf(rx + px[p], (float)WW, -0.5f);
            float y = fmaf(ry + py[p], (float)HH, -0.5f);
            float x0f = floorf(x), y0f = floorf(y);
            float fx = x - x0f, fy = y - y0f;
            int ix = (int)x0f, iy = (int)y0f;
            int ix0 = min(max(ix, 0), WW - 1);
            int ix1 = min(max(ix + 1, 0), WW - 1);
            int iy0 = min(max(iy, 0), HH - 1);
            int iy1 = min(max(iy + 1, 0), HH - 1);
            float wx0 = (1.f - fx) * (((ix >= 0) & (ix < WW)) ? 1.f : 0.f);
            float wx1 = fx * (((ix + 1 >= 0) & (ix + 1 < WW)) ? 1.f : 0.f);
            float wy0 = (1.f - fy) * (((iy >= 0) & (iy < HH)) ? 1.f : 0.f);
            float wy1 = fy * (((iy + 1 >= 0) & (iy + 1 < HH)) ? 1.f : 0.f);
            const ushort4 u00 = fcam[(iy0 * WW + ix0) * (CCH / 4)];
            const ushort4 u01 = fcam[(iy0 * WW + ix1) * (CCH / 4)];
            const ushort4 u10 = fcam[(iy1 * WW + ix0) * (CCH / 4)];
            const ushort4 u11 = fcam[(iy1 * WW + ix1) * (CCH / 4)];
            float a00 = wgt * wy0 * wx0;
            float a01 = wgt * wy0 * wx1;
            float a10 = wgt * wy1 * wx0;
            float a11 = wgt * wy1 * wx1;
            ax = fmaf(a00, bf2f(u00.x), ax); ay = fmaf(a00, bf2f(u00.y), ay);
            az = fmaf(a00, bf2f(u00.z), az); aw = fmaf(a00, bf2f(u00.w), aw);
            ax = fmaf(a01, bf2f(u01.x), ax); ay = fmaf(a01, bf2f(u01.y), ay);
            az = fmaf(a01, bf2f(u01.z), az); aw = fmaf(a01, bf2f(u01.w), aw);
            ax = fmaf(a10, bf2f(u10.x), ax); ay = fmaf(a10, bf2f(u10.y), ay);
            az = fmaf(a10, bf2f(u10.z), az); aw = fmaf(a10, bf2f(u10.w), aw);
            ax = fmaf(a11, bf2f(u11.x), ax); ay = fmaf(a11, bf2f(u11.y), ay);
            az = fmaf(a11, bf2f(u11.z), az); aw = fmaf(a11, bf2f(u11.w), aw);
        }
    }
    *(float4*)outp = make_float4(ax * inv, ay * inv, az * inv, aw * inv);
}

// Register-blocked f32 GEMM for the output projection, with the 6-camera sum
// fused into staging and the per-row 1/count folded into the epilogue.
__global__ void __launch_bounds__(256) outproj3_k(const float* __restrict__ cam_out,
                                                  const int* __restrict__ bev,
                                                  const float* __restrict__ outT,  // [256][256]
                                                  const float* __restrict__ outB,
                                                  float* __restrict__ out, int N) {
    __shared__ float ft[64][32][4];
    __shared__ float inv_s[32];
    int t = threadIdx.x;
    int w = t >> 6, l = t & 63;
    int m0 = blockIdx.x * 32;
    int col = blockIdx.y * 64 + l;    // 0..255

    if (t < 32) {
        int gm = m0 + t;
        int cnt = 0;
        if (gm < N) {
#pragma unroll
            for (int cam = 0; cam < CAMS; cam++) {
                const int* bv = bev + ((long)cam * N + gm) * 4;
                cnt += (bv[0] | bv[1] | bv[2] | bv[3]) ? 1 : 0;
            }
        }
        inv_s[t] = 1.f / (float)max(cnt, 1);
    }

#pragma unroll
    for (int i = 0; i < 8; i++) {
        int mm = i * 4 + w;           // wave-uniform
        int gm = m0 + mm;
        float4 s = make_float4(0.f, 0.f, 0.f, 0.f);
        if (gm < N) {
#pragma unroll
            for (int cam = 0; cam < CAMS; cam++) {
                const float4 v = *(const float4*)(cam_out + ((long)cam * N + gm) * CCH + (l << 2));
                s.x += v.x; s.y += v.y; s.z += v.z; s.w += v.w;
            }
        }
        *(float4*)&ft[l][mm ^ (l & 31)][0] = s;
    }
    __syncthreads();

    int mb = w * 8;
    float acc[8] = {0.f, 0.f, 0.f, 0.f, 0.f, 0.f, 0.f, 0.f};
#pragma unroll 2
    for (int jg = 0; jg < 64; jg++) {
        const float* rp = outT + (long)(jg * 4) * CCH + col;
        float w0 = rp[0];
        float w1 = rp[CCH];
        float w2 = rp[2 * CCH];
        float w3 = rp[3 * CCH];
        int sw = jg & 31;
#pragma unroll
        for (int r = 0; r < 8; r++) {
            const float4 qv = *(const float4*)&ft[jg][(mb + r) ^ sw][0];
            acc[r] = fmaf(qv.w, w3, fmaf(qv.z, w2, fmaf(qv.y, w1, fmaf(qv.x, w0, acc[r]))));
        }
    }

    float b = outB[col];
#pragma unroll
    for (int r = 0; r < 8; r++) {
        int gm = m0 + mb + r;
        if (gm < N) out[(long)gm * CCH + col] = fmaf(acc[r], inv_s[mb + r], b);
    }
}

extern "C" void kernel_launch(void* const* d_in, const int* in_sizes, int n_in,
                              void* d_out, int out_size, void* d_ws, size_t ws_size,
                              hipStream_t stream) {
    const float* query    = (const float*)d_in[0];
    const float* imfeat   = (const float*)d_in[1];
    const float* refp     = (const float*)d_in[2];
    const int*   bev      = (const int*)d_in[3];
    const float* offset_w = (const float*)d_in[4];
    const float* offset_b = (const float*)d_in[5];
    const float* weight_w = (const float*)d_in[6];
    const float* weight_b = (const float*)d_in[7];
    const float* out_w    = (const float*)d_in[8];
    const float* out_b    = (const float*)d_in[9];
    float* out = (float*)d_out;

    int N = in_sizes[0] / CCH;  // 2500

    float* ws = (float*)d_ws;
    unsigned short* feat_t = (unsigned short*)ws;              // 6*3680*256 bf16
    float* WC     = ws + (size_t)CAMS * NPIX * CCH / 2;        // 256*384
    float* outT   = WC + (size_t)CCH * NC;                     // 256*256
    float* offs   = outT + (size_t)CCH * CCH;                  // N*256
    float* wl     = offs + (size_t)N * CCH;                    // N*128
    float* camob  = wl + (size_t)N * 128;                      // CAMS*N*256

    feat_transpose_k<<<dim3((NPIX + 63) / 64, CCH / 64, CAMS), 256, 0, stream>>>(imfeat, feat_t);
    wtrans_k<<<40, 256, 0, stream>>>(offset_w, weight_w, out_w, WC, outT);

    int mblocks = (N + 31) / 32;   // 79
    qgemm3_k<<<dim3(mblocks, 6), 256, 0, stream>>>(query, WC, offset_b, weight_b, offs, wl, N);

    int T = CAMS * N;
    int per_xcd = (T + 7) / 8;
    int blocks = 8 * ((per_xcd + 3) / 4);
    sample_cam_k<<<blocks, 256, 0, stream>>>(feat_t, refp, bev, offs, wl, camob,
                                             N, per_xcd);

    outproj3_k<<<dim3(mblocks, 4), 256, 0, stream>>>(camob, bev, outT, out_b, out, N);
}